// Round 1
// baseline (139.982 us; speedup 1.0000x reference)
//
#include <hip/hip_runtime.h>

// Problem constants
#define B 4
#define S 8192
#define D 256
#define H 8

#define NC1 128      // s-chunks for col-stats pass (64 rows each)
#define SCH1 64
#define NC3 128      // s-chunks for Z pass
#define SCH3 64
#define ROWS5 16     // rows per block in the final pass
#define LOG2E 1.4426950408889634f

// Workspace layout (float offsets)
#define WS_WQ    0
#define WS_WV    8
#define WS_QMAX  16
#define WS_QMIN  (WS_QMAX + B*D)
#define WS_CV    (WS_QMIN + B*D)
#define WS_KC    (WS_CV + B*D)
#define WS_P1    (WS_KC + B*H*D)
#define WS_P2    (WS_P1 + NC1*B*D)
#define WS_P3    (WS_P2 + NC1*B*D)
#define WS_PZ    (WS_P3 + NC1*B*D)
#define WS_TOTAL (WS_PZ + B*NC3*H*D)   // ~1.45M floats ~ 5.8 MB

// ---------------------------------------------------------------------------
// K0: per-head weight sums  wq[h] = sum(q_weights[h]), wv[h] = sum(v_weights[h])
__global__ __launch_bounds__(256) void k0_wsum(const float* __restrict__ qw,
                                               const float* __restrict__ vw,
                                               float* __restrict__ ws) {
    int which = blockIdx.x >> 3;      // 0 -> wq, 1 -> wv
    int h = blockIdx.x & 7;
    const float* src = (which ? vw : qw) + (size_t)h * D * D;
    int t = threadIdx.x;
    float sm = 0.f;
    for (int i = t; i < D * D; i += 256) sm += src[i];
    #pragma unroll
    for (int off = 32; off; off >>= 1) sm += __shfl_down(sm, off, 64);
    __shared__ float red[4];
    if ((t & 63) == 0) red[t >> 6] = sm;
    __syncthreads();
    if (t == 0) ws[(which ? WS_WV : WS_WQ) + h] = red[0] + red[1] + red[2] + red[3];
}

// ---------------------------------------------------------------------------
// K1: per-(b,d) column partials over an s-chunk: max(q), min(q), sum(v)
__global__ __launch_bounds__(256) void k1_colstats(const float* __restrict__ q,
                                                   const float* __restrict__ v,
                                                   float* __restrict__ ws) {
    int bc = blockIdx.x;
    int b = bc / NC1, c = bc % NC1;
    int t = threadIdx.x, wave = t >> 6, lane = t & 63;
    int s0 = c * SCH1 + wave * (SCH1 / 4);   // each wave: 16 rows
    const float4* q4 = (const float4*)(q + ((size_t)b * S + s0) * D);
    const float4* v4 = (const float4*)(v + ((size_t)b * S + s0) * D);
    float4 qmx = make_float4(-3.4e38f, -3.4e38f, -3.4e38f, -3.4e38f);
    float4 qmn = make_float4(3.4e38f, 3.4e38f, 3.4e38f, 3.4e38f);
    float4 vs  = make_float4(0.f, 0.f, 0.f, 0.f);
    #pragma unroll 4
    for (int j = 0; j < SCH1 / 4; ++j) {
        float4 a = q4[(size_t)j * 64 + lane];
        qmx.x = fmaxf(qmx.x, a.x); qmx.y = fmaxf(qmx.y, a.y);
        qmx.z = fmaxf(qmx.z, a.z); qmx.w = fmaxf(qmx.w, a.w);
        qmn.x = fminf(qmn.x, a.x); qmn.y = fminf(qmn.y, a.y);
        qmn.z = fminf(qmn.z, a.z); qmn.w = fminf(qmn.w, a.w);
        float4 bv = v4[(size_t)j * 64 + lane];
        vs.x += bv.x; vs.y += bv.y; vs.z += bv.z; vs.w += bv.w;
    }
    __shared__ float lq[4 * 256], lm[4 * 256], lv[4 * 256];
    int di = lane * 4;
    lq[wave * 256 + di + 0] = qmx.x; lq[wave * 256 + di + 1] = qmx.y;
    lq[wave * 256 + di + 2] = qmx.z; lq[wave * 256 + di + 3] = qmx.w;
    lm[wave * 256 + di + 0] = qmn.x; lm[wave * 256 + di + 1] = qmn.y;
    lm[wave * 256 + di + 2] = qmn.z; lm[wave * 256 + di + 3] = qmn.w;
    lv[wave * 256 + di + 0] = vs.x;  lv[wave * 256 + di + 1] = vs.y;
    lv[wave * 256 + di + 2] = vs.z;  lv[wave * 256 + di + 3] = vs.w;
    __syncthreads();
    int d = t;
    float mx = fmaxf(fmaxf(lq[d], lq[256 + d]), fmaxf(lq[512 + d], lq[768 + d]));
    float mn = fminf(fminf(lm[d], lm[256 + d]), fminf(lm[512 + d], lm[768 + d]));
    float sm = lv[d] + lv[256 + d] + lv[512 + d] + lv[768 + d];
    ws[WS_P1 + (size_t)bc * D + d] = mx;
    ws[WS_P2 + (size_t)bc * D + d] = mn;
    ws[WS_P3 + (size_t)bc * D + d] = sm;
}

// ---------------------------------------------------------------------------
// K2: reduce chunk partials -> qmax[b,d], qmin[b,d], Cv[b,d] = D * Vsum[b,d]
__global__ __launch_bounds__(256) void k2_reduce(float* __restrict__ ws) {
    int b = blockIdx.x, d = threadIdx.x;
    float mx = -3.4e38f, mn = 3.4e38f, sm = 0.f;
    for (int c = 0; c < NC1; ++c) {
        size_t i = (size_t)(b * NC1 + c) * D + d;
        mx = fmaxf(mx, ws[WS_P1 + i]);
        mn = fminf(mn, ws[WS_P2 + i]);
        sm += ws[WS_P3 + i];
    }
    ws[WS_QMAX + b * D + d] = mx;
    ws[WS_QMIN + b * D + d] = mn;
    ws[WS_CV + b * D + d] = sm * (float)D;
}

// ---------------------------------------------------------------------------
// K3: partial softmax denominators Z[b,h,d] over an s-chunk
__global__ __launch_bounds__(256) void k3_zpart(const float* __restrict__ q,
                                                float* __restrict__ ws) {
    int bc = blockIdx.x;
    int b = bc / NC3, c = bc % NC3;
    int d = threadIdx.x;
    float qmx = ws[WS_QMAX + b * D + d];
    float qmn = ws[WS_QMIN + b * D + d];
    float a[H], cc[H], z[H];
    #pragma unroll
    for (int h = 0; h < H; ++h) {
        float w = ws[WS_WQ + h];
        float m = (w >= 0.f) ? w * qmx : w * qmn;   // max_s of w*q[b,s,d]
        a[h] = w * LOG2E;
        cc[h] = -m * LOG2E;
        z[h] = 0.f;
    }
    const float* qp = q + ((size_t)b * S + (size_t)c * SCH3) * D + d;
    for (int j = 0; j < SCH3; ++j) {
        float qv = qp[(size_t)j * D];
        #pragma unroll
        for (int h = 0; h < H; ++h) z[h] += exp2f(fmaf(qv, a[h], cc[h]));
    }
    #pragma unroll
    for (int h = 0; h < H; ++h)
        ws[WS_PZ + (size_t)(bc * H + h) * D + d] = z[h];
}

// ---------------------------------------------------------------------------
// K4: reduce Z partials -> kc[b,h,d] = -M*log2e - log2(Z)
__global__ __launch_bounds__(256) void k4_kc(float* __restrict__ ws) {
    int b = blockIdx.x / H, h = blockIdx.x % H;
    int d = threadIdx.x;
    float z = 0.f;
    for (int c = 0; c < NC3; ++c)
        z += ws[WS_PZ + (size_t)((b * NC3 + c) * H + h) * D + d];
    float w = ws[WS_WQ + h];
    float m = (w >= 0.f) ? w * ws[WS_QMAX + b * D + d] : w * ws[WS_QMIN + b * D + d];
    ws[WS_KC + (b * H + h) * D + d] = -m * LOG2E - log2f(z);
}

// ---------------------------------------------------------------------------
// K5: per row s: Qs[h] = sum_d exp2(q*a[h] + kc[h,d]);  A[h]=wv[h]*Qs[h];
//     out[b,s,v] = Cv>=0 ? Cv*maxA : Cv*minA
__global__ __launch_bounds__(256) void k5_final(const float* __restrict__ q,
                                                const float* __restrict__ ws,
                                                float* __restrict__ out) {
    const int nt = S / ROWS5;                 // 512 tiles per batch
    int b = blockIdx.x / nt, tile = blockIdx.x % nt;
    int t = threadIdx.x, wave = t >> 6, lane = t & 63;

    float a[H], wv[H];
    float4 kc[H];
    #pragma unroll
    for (int h = 0; h < H; ++h) {
        a[h] = ws[WS_WQ + h] * LOG2E;
        wv[h] = ws[WS_WV + h];
        kc[h] = *(const float4*)&ws[WS_KC + (b * H + h) * D + lane * 4];
    }
    float4 cv = *(const float4*)&ws[WS_CV + b * D + lane * 4];

    int s0 = tile * ROWS5 + wave * (ROWS5 / 4);
    const float4* qp = (const float4*)(q + ((size_t)b * S + s0) * D) + lane;
    float4* op = (float4*)(out + ((size_t)b * S + s0) * D) + lane;

    for (int r = 0; r < ROWS5 / 4; ++r) {
        float4 qv = qp[(size_t)r * 64];
        float p[H];
        #pragma unroll
        for (int h = 0; h < H; ++h) {
            p[h] = exp2f(fmaf(qv.x, a[h], kc[h].x))
                 + exp2f(fmaf(qv.y, a[h], kc[h].y))
                 + exp2f(fmaf(qv.z, a[h], kc[h].z))
                 + exp2f(fmaf(qv.w, a[h], kc[h].w));
        }
        #pragma unroll
        for (int off = 32; off; off >>= 1) {
            #pragma unroll
            for (int h = 0; h < H; ++h) p[h] += __shfl_xor(p[h], off, 64);
        }
        float amax = -3.4e38f, amin = 3.4e38f;
        #pragma unroll
        for (int h = 0; h < H; ++h) {
            float A = wv[h] * p[h];
            amax = fmaxf(amax, A);
            amin = fminf(amin, A);
        }
        float4 o;
        o.x = (cv.x >= 0.f) ? cv.x * amax : cv.x * amin;
        o.y = (cv.y >= 0.f) ? cv.y * amax : cv.y * amin;
        o.z = (cv.z >= 0.f) ? cv.z * amax : cv.z * amin;
        o.w = (cv.w >= 0.f) ? cv.w * amax : cv.w * amin;
        op[(size_t)r * 64] = o;
    }
}

// ---------------------------------------------------------------------------
extern "C" void kernel_launch(void* const* d_in, const int* in_sizes, int n_in,
                              void* d_out, int out_size, void* d_ws, size_t ws_size,
                              hipStream_t stream) {
    const float* q  = (const float*)d_in[0];
    // d_in[1] (k) and d_in[4] (k_weights) are provably unused: softmax over s sums to 1.
    const float* v  = (const float*)d_in[2];
    const float* qw = (const float*)d_in[3];
    const float* vw = (const float*)d_in[5];
    float* out = (float*)d_out;
    float* ws  = (float*)d_ws;

    k0_wsum<<<16, 256, 0, stream>>>(qw, vw, ws);
    k1_colstats<<<B * NC1, 256, 0, stream>>>(q, v, ws);
    k2_reduce<<<B, 256, 0, stream>>>(ws);
    k3_zpart<<<B * NC3, 256, 0, stream>>>(q, ws);
    k4_kc<<<B * H, 256, 0, stream>>>(ws);
    k5_final<<<B * (S / ROWS5), 256, 0, stream>>>(q, ws, out);
}

// Round 2
// 82.580 us; speedup vs baseline: 1.6951x; 1.6951x over previous
//
#include <hip/hip_runtime.h>

// Problem constants
#define B 4
#define S 8192
#define D 256
#define H 8

#define NC0 16       // chunks per (which,h) for weight-sum pass
#define NC1 128      // s-chunks for col-stats pass (64 rows each)
#define SCH1 64
#define NC3 128      // s-chunks for Z pass
#define SCH3 64
#define ROWS5 16     // rows per block in the final pass
#define LOG2E 1.4426950408889634f

// Workspace layout (float offsets)
#define WS_WQ    0
#define WS_WV    8
#define WS_QMAX  16
#define WS_QMIN  (WS_QMAX + B*D)
#define WS_CV    (WS_QMIN + B*D)
#define WS_KC    (WS_CV + B*D)
#define WS_P1    (WS_KC + B*H*D)
#define WS_P2    (WS_P1 + NC1*B*D)
#define WS_P3    (WS_P2 + NC1*B*D)
#define WS_PZ    (WS_P3 + NC1*B*D)
#define WS_P0    (WS_PZ + B*NC3*H*D)
#define WS_TOTAL (WS_P0 + 2*H*NC0)

// ---------------------------------------------------------------------------
// K0a: partial weight sums. 256 blocks, each sums a 4096-float chunk of one
// (which, h) weight matrix via float4 loads (4 in flight / thread).
__global__ __launch_bounds__(256) void k0a_wpart(const float* __restrict__ qw,
                                                 const float* __restrict__ vw,
                                                 float* __restrict__ ws) {
    int blk = blockIdx.x;                 // 0 .. 2*H*NC0-1
    int which = blk / (H * NC0);
    int rest = blk % (H * NC0);
    int h = rest / NC0, c = rest % NC0;
    const float4* src = (const float4*)((which ? vw : qw) + (size_t)h * D * D)
                        + (size_t)c * 1024;
    int t = threadIdx.x;
    float sm = 0.f;
    #pragma unroll
    for (int j = 0; j < 4; ++j) {
        float4 a = src[j * 256 + t];
        sm += (a.x + a.y) + (a.z + a.w);
    }
    #pragma unroll
    for (int off = 32; off; off >>= 1) sm += __shfl_down(sm, off, 64);
    __shared__ float red[4];
    if ((t & 63) == 0) red[t >> 6] = sm;
    __syncthreads();
    if (t == 0) ws[WS_P0 + blk] = red[0] + red[1] + red[2] + red[3];
}

// ---------------------------------------------------------------------------
// K1: per-(b,d) column partials over an s-chunk: max(q), min(q), sum(v)
__global__ __launch_bounds__(256) void k1_colstats(const float* __restrict__ q,
                                                   const float* __restrict__ v,
                                                   float* __restrict__ ws) {
    int bc = blockIdx.x;
    int b = bc / NC1, c = bc % NC1;
    int t = threadIdx.x, wave = t >> 6, lane = t & 63;
    int s0 = c * SCH1 + wave * (SCH1 / 4);   // each wave: 16 rows
    const float4* q4 = (const float4*)(q + ((size_t)b * S + s0) * D);
    const float4* v4 = (const float4*)(v + ((size_t)b * S + s0) * D);
    float4 qmx = make_float4(-3.4e38f, -3.4e38f, -3.4e38f, -3.4e38f);
    float4 qmn = make_float4(3.4e38f, 3.4e38f, 3.4e38f, 3.4e38f);
    float4 vs  = make_float4(0.f, 0.f, 0.f, 0.f);
    #pragma unroll 4
    for (int j = 0; j < SCH1 / 4; ++j) {
        float4 a = q4[(size_t)j * 64 + lane];
        qmx.x = fmaxf(qmx.x, a.x); qmx.y = fmaxf(qmx.y, a.y);
        qmx.z = fmaxf(qmx.z, a.z); qmx.w = fmaxf(qmx.w, a.w);
        qmn.x = fminf(qmn.x, a.x); qmn.y = fminf(qmn.y, a.y);
        qmn.z = fminf(qmn.z, a.z); qmn.w = fminf(qmn.w, a.w);
        float4 bv = v4[(size_t)j * 64 + lane];
        vs.x += bv.x; vs.y += bv.y; vs.z += bv.z; vs.w += bv.w;
    }
    __shared__ float lq[4 * 256], lm[4 * 256], lv[4 * 256];
    int di = lane * 4;
    lq[wave * 256 + di + 0] = qmx.x; lq[wave * 256 + di + 1] = qmx.y;
    lq[wave * 256 + di + 2] = qmx.z; lq[wave * 256 + di + 3] = qmx.w;
    lm[wave * 256 + di + 0] = qmn.x; lm[wave * 256 + di + 1] = qmn.y;
    lm[wave * 256 + di + 2] = qmn.z; lm[wave * 256 + di + 3] = qmn.w;
    lv[wave * 256 + di + 0] = vs.x;  lv[wave * 256 + di + 1] = vs.y;
    lv[wave * 256 + di + 2] = vs.z;  lv[wave * 256 + di + 3] = vs.w;
    __syncthreads();
    int d = t;
    float mx = fmaxf(fmaxf(lq[d], lq[256 + d]), fmaxf(lq[512 + d], lq[768 + d]));
    float mn = fminf(fminf(lm[d], lm[256 + d]), fminf(lm[512 + d], lm[768 + d]));
    float sm = lv[d] + lv[256 + d] + lv[512 + d] + lv[768 + d];
    ws[WS_P1 + (size_t)bc * D + d] = mx;
    ws[WS_P2 + (size_t)bc * D + d] = mn;
    ws[WS_P3 + (size_t)bc * D + d] = sm;
}

// ---------------------------------------------------------------------------
// K2: reduce chunk partials -> qmax[b,d], qmin[b,d], Cv[b,d] = D * Vsum[b,d]
//     Block 0 additionally finishes the weight sums (wq[h], wv[h]).
__global__ __launch_bounds__(256) void k2_reduce(float* __restrict__ ws) {
    int b = blockIdx.x, d = threadIdx.x;
    float mx = -3.4e38f, mn = 3.4e38f, sm = 0.f;
    for (int c = 0; c < NC1; ++c) {
        size_t i = (size_t)(b * NC1 + c) * D + d;
        mx = fmaxf(mx, ws[WS_P1 + i]);
        mn = fminf(mn, ws[WS_P2 + i]);
        sm += ws[WS_P3 + i];
    }
    ws[WS_QMAX + b * D + d] = mx;
    ws[WS_QMIN + b * D + d] = mn;
    ws[WS_CV + b * D + d] = sm * (float)D;
    if (b == 0 && d < 2 * H) {
        float s = 0.f;
        for (int c = 0; c < NC0; ++c) s += ws[WS_P0 + d * NC0 + c];
        int which = d / H, h = d % H;
        ws[(which ? WS_WV : WS_WQ) + h] = s;
    }
}

// ---------------------------------------------------------------------------
// K3: partial softmax denominators Z[b,h,d] over an s-chunk
__global__ __launch_bounds__(256) void k3_zpart(const float* __restrict__ q,
                                                float* __restrict__ ws) {
    int bc = blockIdx.x;
    int b = bc / NC3, c = bc % NC3;
    int d = threadIdx.x;
    float qmx = ws[WS_QMAX + b * D + d];
    float qmn = ws[WS_QMIN + b * D + d];
    float a[H], cc[H], z[H];
    #pragma unroll
    for (int h = 0; h < H; ++h) {
        float w = ws[WS_WQ + h];
        float m = (w >= 0.f) ? w * qmx : w * qmn;   // max_s of w*q[b,s,d]
        a[h] = w * LOG2E;
        cc[h] = -m * LOG2E;
        z[h] = 0.f;
    }
    const float* qp = q + ((size_t)b * S + (size_t)c * SCH3) * D + d;
    for (int j = 0; j < SCH3; ++j) {
        float qv = qp[(size_t)j * D];
        #pragma unroll
        for (int h = 0; h < H; ++h) z[h] += exp2f(fmaf(qv, a[h], cc[h]));
    }
    #pragma unroll
    for (int h = 0; h < H; ++h)
        ws[WS_PZ + (size_t)(bc * H + h) * D + d] = z[h];
}

// ---------------------------------------------------------------------------
// K4: reduce Z partials -> kc[b,h,d] = -M*log2e - log2(Z)
__global__ __launch_bounds__(256) void k4_kc(float* __restrict__ ws) {
    int b = blockIdx.x / H, h = blockIdx.x % H;
    int d = threadIdx.x;
    float z = 0.f;
    for (int c = 0; c < NC3; ++c)
        z += ws[WS_PZ + (size_t)((b * NC3 + c) * H + h) * D + d];
    float w = ws[WS_WQ + h];
    float m = (w >= 0.f) ? w * ws[WS_QMAX + b * D + d] : w * ws[WS_QMIN + b * D + d];
    ws[WS_KC + (b * H + h) * D + d] = -m * LOG2E - log2f(z);
}

// ---------------------------------------------------------------------------
// K5: per row s: Qs[h] = sum_d exp2(q*a[h] + kc[h,d]);  A[h]=wv[h]*Qs[h];
//     out[b,s,v] = Cv>=0 ? Cv*maxA : Cv*minA
__global__ __launch_bounds__(256) void k5_final(const float* __restrict__ q,
                                                const float* __restrict__ ws,
                                                float* __restrict__ out) {
    const int nt = S / ROWS5;                 // 512 tiles per batch
    int b = blockIdx.x / nt, tile = blockIdx.x % nt;
    int t = threadIdx.x, wave = t >> 6, lane = t & 63;

    float a[H], wv[H];
    float4 kc[H];
    #pragma unroll
    for (int h = 0; h < H; ++h) {
        a[h] = ws[WS_WQ + h] * LOG2E;
        wv[h] = ws[WS_WV + h];
        kc[h] = *(const float4*)&ws[WS_KC + (b * H + h) * D + lane * 4];
    }
    float4 cv = *(const float4*)&ws[WS_CV + b * D + lane * 4];

    int s0 = tile * ROWS5 + wave * (ROWS5 / 4);
    const float4* qp = (const float4*)(q + ((size_t)b * S + s0) * D) + lane;
    float4* op = (float4*)(out + ((size_t)b * S + s0) * D) + lane;

    for (int r = 0; r < ROWS5 / 4; ++r) {
        float4 qv = qp[(size_t)r * 64];
        float p[H];
        #pragma unroll
        for (int h = 0; h < H; ++h) {
            p[h] = exp2f(fmaf(qv.x, a[h], kc[h].x))
                 + exp2f(fmaf(qv.y, a[h], kc[h].y))
                 + exp2f(fmaf(qv.z, a[h], kc[h].z))
                 + exp2f(fmaf(qv.w, a[h], kc[h].w));
        }
        #pragma unroll
        for (int off = 32; off; off >>= 1) {
            #pragma unroll
            for (int h = 0; h < H; ++h) p[h] += __shfl_xor(p[h], off, 64);
        }
        float amax = -3.4e38f, amin = 3.4e38f;
        #pragma unroll
        for (int h = 0; h < H; ++h) {
            float A = wv[h] * p[h];
            amax = fmaxf(amax, A);
            amin = fminf(amin, A);
        }
        float4 o;
        o.x = (cv.x >= 0.f) ? cv.x * amax : cv.x * amin;
        o.y = (cv.y >= 0.f) ? cv.y * amax : cv.y * amin;
        o.z = (cv.z >= 0.f) ? cv.z * amax : cv.z * amin;
        o.w = (cv.w >= 0.f) ? cv.w * amax : cv.w * amin;
        op[(size_t)r * 64] = o;
    }
}

// ---------------------------------------------------------------------------
extern "C" void kernel_launch(void* const* d_in, const int* in_sizes, int n_in,
                              void* d_out, int out_size, void* d_ws, size_t ws_size,
                              hipStream_t stream) {
    const float* q  = (const float*)d_in[0];
    // d_in[1] (k) and d_in[4] (k_weights) are provably unused: softmax over s sums to 1.
    const float* v  = (const float*)d_in[2];
    const float* qw = (const float*)d_in[3];
    const float* vw = (const float*)d_in[5];
    float* out = (float*)d_out;
    float* ws  = (float*)d_ws;

    k0a_wpart<<<2 * H * NC0, 256, 0, stream>>>(qw, vw, ws);
    k1_colstats<<<B * NC1, 256, 0, stream>>>(q, v, ws);
    k2_reduce<<<B, 256, 0, stream>>>(ws);
    k3_zpart<<<B * NC3, 256, 0, stream>>>(q, ws);
    k4_kc<<<B * H, 256, 0, stream>>>(ws);
    k5_final<<<B * (S / ROWS5), 256, 0, stream>>>(q, ws, out);
}